// Round 4
// baseline (447.749 us; speedup 1.0000x reference)
//
#include <hip/hip_runtime.h>
#include <cstdint>
#include <cstddef>

#define B_ 64
#define N_ 16384
#define C_ 10
#define D_ 8
#define E_ 16
#define NTB_ 8                  // n per chunk
#define NCHK_ 4                 // chunks per block
#define NPB_ (NTB_ * NCHK_)     // 32 n per block
#define GRID_ (N_ / NPB_)       // 512 blocks
#define SVOL_ (B_ * C_ * E_)    // 10240 floats

typedef __attribute__((ext_vector_type(8))) short short8;
typedef __attribute__((ext_vector_type(4))) float f32x4;

__device__ __forceinline__ uint32_t f2bf(float f) {
  uint32_t u = __builtin_bit_cast(uint32_t, f);
  return (u + 0x7fffu + ((u >> 16) & 1u)) >> 16;   // RNE
}
__device__ __forceinline__ uint32_t pack2(float lo, float hi) {
  return f2bf(lo) | (f2bf(hi) << 16);
}

// ---------------------------------------------------------------------------
// One routing pass. Block = 32 n x all 64 b, 4 waves; wave w owns b-tile
// b = w*16 + (lane&15). Per n, per class c: one mfma_f32_16x16x32_bf16 with
//   A[row=e][k=d] = W[n,c,d,e]  (lanes<16 hold d=0..7; lanes>=16 zero)
//   B[k=d][col=b] = x[b,n,d]
//   D[row=e][col=b] = u_hat[b,n,c,e]  (lane: b=lane&15, e=(lane>>4)*4+reg)
// ITER 0: acc[c] accumulated directly in the MFMA C operand (c_uniform=0.1
// applied at flush). ITER 1: logits via in-register 4-dot + shfl_xor(32) +
// shfl_xor(16) (e-group reduction), softmax per lane, FMA-accumulate.
// W/x staged to LDS in frag order (bf16, double-buffered).
// ---------------------------------------------------------------------------
template <int ITER>
__global__ __launch_bounds__(256, 2) void accum_kernel(
    const float* __restrict__ x,     // [B][N][D]
    const float* __restrict__ W,     // [N][C][D][E]
    const float* __restrict__ vacc,  // [B][C][E]
    float* __restrict__ scopy,       // [ncopy][B][C][E]
    int ncopy)
{
  __shared__ uint32_t wbuf[2][NTB_ * C_ * E_ * 4];  // [n][c][e][d2]  2x20 KB
  __shared__ uint32_t xbuf[2][NTB_ * B_ * 4];       // [n][b][d2]     2x8 KB

  const int tid = threadIdx.x;
  const int lane = tid & 63;
  const int wv = tid >> 6;      // b-tile 0..3
  const int l15 = lane & 15;
  const int eg = lane >> 4;     // e-group 0..3
  const int nblock = blockIdx.x * NPB_;

  f32x4 vf[C_];
  if (ITER) {
    const int b = wv * 16 + l15;
#pragma unroll
    for (int c = 0; c < C_; ++c)
      vf[c] = *(const f32x4*)&vacc[(b * C_ + c) * E_ + eg * 4];
  }

  f32x4 acc[C_];
#pragma unroll
  for (int c = 0; c < C_; ++c) acc[c] = (f32x4){0.f, 0.f, 0.f, 0.f};

  short8 xf = (short8){0, 0, 0, 0, 0, 0, 0, 0};
  short8 wf[C_];
#pragma unroll
  for (int c = 0; c < C_; ++c) wf[c] = xf;

  auto stage = [&](int pb, int nbase) {
    // W: 5120 u32 items; consecutive tid -> consecutive e (coalesced 64B)
#pragma unroll
    for (int it = 0; it < 20; ++it) {
      int i = it * 256 + tid;
      int n = i / 640, r = i - n * 640;
      int c = r >> 6, r2 = r & 63;
      int d2 = r2 >> 4, e = r2 & 15;
      const float* p = W + (((size_t)(nbase + n) * C_ + c) << 7) + d2 * 32 + e;
      wbuf[pb][((n * C_ + c) * E_ + e) * 4 + d2] = pack2(p[0], p[16]);
    }
    // x: 2048 u32 items; per b: 64 consecutive floats (coalesced)
#pragma unroll
    for (int it = 0; it < 8; ++it) {
      int i = it * 256 + tid;
      int b = i >> 5, r = i & 31;
      int n = r >> 2, d2 = r & 3;
      const float* p = x + ((size_t)b * N_ + nbase + n) * D_ + d2 * 2;
      xbuf[pb][(n * B_ + b) * 4 + d2] = pack2(p[0], p[1]);
    }
  };

  stage(0, nblock);
  __syncthreads();

  for (int ch = 0; ch < NCHK_; ++ch) {
    if (ch + 1 < NCHK_) stage((ch + 1) & 1, nblock + (ch + 1) * NTB_);
    const int pb = ch & 1;
    for (int n = 0; n < NTB_; ++n) {
      if (lane < 16) {  // lanes >= 16 keep zero frags
        xf = *(const short8*)&xbuf[pb][(n * B_ + wv * 16 + l15) * 4];
#pragma unroll
        for (int c = 0; c < C_; ++c)
          wf[c] = *(const short8*)&wbuf[pb][((n * C_ + c) * E_ + l15) * 4];
      }
      if (ITER == 0) {
#pragma unroll
        for (int c = 0; c < C_; ++c)
          acc[c] = __builtin_amdgcn_mfma_f32_16x16x32_bf16(wf[c], xf, acc[c], 0, 0, 0);
      } else {
        f32x4 u[C_];
#pragma unroll
        for (int c = 0; c < C_; ++c)
          u[c] = __builtin_amdgcn_mfma_f32_16x16x32_bf16(
              wf[c], xf, (f32x4){0.f, 0.f, 0.f, 0.f}, 0, 0, 0);
        float ew[C_];
        float ssum = 0.f;
#pragma unroll
        for (int c = 0; c < C_; ++c) {
          float t = u[c][0] * vf[c][0] + u[c][1] * vf[c][1] +
                    u[c][2] * vf[c][2] + u[c][3] * vf[c][3];
          t += __shfl_xor(t, 32);   // e-group bit 1
          t += __shfl_xor(t, 16);   // e-group bit 0 -> full sum over e
          ew[c] = __expf(t);
          ssum += ew[c];
        }
        float inv = __builtin_amdgcn_rcpf(ssum);
#pragma unroll
        for (int c = 0; c < C_; ++c) {
          float cw = ew[c] * inv;
          acc[c][0] = fmaf(cw, u[c][0], acc[c][0]);
          acc[c][1] = fmaf(cw, u[c][1], acc[c][1]);
          acc[c][2] = fmaf(cw, u[c][2], acc[c][2]);
          acc[c][3] = fmaf(cw, u[c][3], acc[c][3]);
        }
      }
    }
    __syncthreads();
  }

  // flush: this thread owns s[b][c][eg*4..eg*4+3] partials for b = wv*16+l15
  const float scale = (ITER == 0) ? 0.1f : 1.0f;
  float* sc = scopy + (size_t)(blockIdx.x & (ncopy - 1)) * SVOL_;
  const int b = wv * 16 + l15;
#pragma unroll
  for (int c = 0; c < C_; ++c) {
#pragma unroll
    for (int r = 0; r < 4; ++r)
      atomicAdd(&sc[(b * C_ + c) * E_ + eg * 4 + r], acc[c][r] * scale);
  }
}

// ---------------------------------------------------------------------------
// Reduce striped s copies, apply squash. 16 consecutive lanes = one capsule.
// MODE 0: vacc = v    MODE 1: vacc += v    MODE 2: out = v
// ---------------------------------------------------------------------------
template <int MODE>
__global__ __launch_bounds__(256) void squash_kernel(
    const float* __restrict__ scopy, int ncopy,
    float* __restrict__ vacc, float* __restrict__ out)
{
  int t = blockIdx.x * 256 + threadIdx.x;  // 0..10239
  float sv = 0.f;
  for (int k = 0; k < ncopy; ++k) sv += scopy[(size_t)k * SVOL_ + t];
  float sq = sv * sv;
  sq += __shfl_xor(sq, 1);
  sq += __shfl_xor(sq, 2);
  sq += __shfl_xor(sq, 4);
  sq += __shfl_xor(sq, 8);
  float scale = sq / (1.f + sq) * rsqrtf(sq + 1e-7f);
  float v = scale * sv;
  if (MODE == 0)      vacc[t] = v;
  else if (MODE == 1) vacc[t] += v;
  else                out[t] = v;
}

extern "C" void kernel_launch(void* const* d_in, const int* in_sizes, int n_in,
                              void* d_out, int out_size, void* d_ws, size_t ws_size,
                              hipStream_t stream)
{
  const float* x = (const float*)d_in[0];  // [64][16384][8]
  const float* W = (const float*)d_in[1];  // [16384][10][8][16]
  float* out = (float*)d_out;              // [64][10][16]

  int ncopy = 64;
  while (ncopy > 1 && (size_t)(ncopy + 1) * SVOL_ * sizeof(float) > ws_size)
    ncopy >>= 1;
  float* s_ws = (float*)d_ws;
  float* vacc = s_ws + (size_t)ncopy * SVOL_;
  const size_t s_bytes = (size_t)ncopy * SVOL_ * sizeof(float);

  // pass 0: uniform c=0.1 -> s0 -> v0
  hipMemsetAsync(s_ws, 0, s_bytes, stream);
  accum_kernel<0><<<GRID_, 256, 0, stream>>>(x, W, vacc, s_ws, ncopy);
  squash_kernel<0><<<SVOL_ / 256, 256, 0, stream>>>(s_ws, ncopy, vacc, out);

  // pass 1: logits = u.v0 -> s1 -> v1; vacc = v0 + v1
  hipMemsetAsync(s_ws, 0, s_bytes, stream);
  accum_kernel<1><<<GRID_, 256, 0, stream>>>(x, W, vacc, s_ws, ncopy);
  squash_kernel<1><<<SVOL_ / 256, 256, 0, stream>>>(s_ws, ncopy, vacc, out);

  // pass 2: logits = u.(v0+v1) -> v2 = output
  hipMemsetAsync(s_ws, 0, s_bytes, stream);
  accum_kernel<1><<<GRID_, 256, 0, stream>>>(x, W, vacc, s_ws, ncopy);
  squash_kernel<2><<<SVOL_ / 256, 256, 0, stream>>>(s_ws, ncopy, vacc, out);
}